// Round 3
// baseline (78.657 us; speedup 1.0000x reference)
//
#include <hip/hip_runtime.h>

#define BATCH 8
#define NATOM 256
#define DF    42
#define H1    64
#define H2    32

typedef float f32x4 __attribute__((ext_vector_type(4)));

__device__ __forceinline__ float softplus_f(float z) {
  return fmaxf(z, 0.f) + log1pf(expf(-fabsf(z)));
}

// ---------------- Kernel 1: per-atom mirrored MLP (fwd + analytic bwd) ----
// grid = B*N/4 blocks, 256 threads (4 waves). One wave per atom.
__global__ __launch_bounds__(256) void k1_mlp(
    const float* __restrict__ image,
    const float* __restrict__ W1, const float* __restrict__ b1,
    const float* __restrict__ W2, const float* __restrict__ b2,
    const float* __restrict__ W3, const float* __restrict__ b3,
    float* __restrict__ dG, float* __restrict__ Ei_ws) {
  __shared__ float sW1 [DF*H1];   // [d][h]
  __shared__ float sW1T[H1*DF];   // [h][d]
  __shared__ float sW2 [H1*H2];   // [h1][h2]
  __shared__ float sW2T[H2*H1];   // [h2][h1]
  __shared__ float sW3[H2], sb1[H1], sb2[H2];

  const int tid = threadIdx.x;
  for (int idx = tid; idx < DF*H1; idx += 256) {
    float w = W1[idx];
    sW1[idx] = w;
    sW1T[(idx & (H1-1))*DF + (idx >> 6)] = w;   // idx = d*64+h
  }
  for (int idx = tid; idx < H1*H2; idx += 256) {
    float w = W2[idx];
    sW2[idx] = w;
    sW2T[(idx & (H2-1))*H1 + (idx >> 5)] = w;   // idx = h1*32+h2
  }
  if (tid < H2)                    { sW3[tid] = W3[tid]; sb2[tid] = b2[tid]; }
  else if (tid >= 64 && tid < 128) { sb1[tid-64] = b1[tid-64]; }
  __syncthreads();

  const int lane = tid & 63;
  const int atom = blockIdx.x * 4 + (tid >> 6);      // 0..B*N-1

  float xv = (lane < DF) ? image[atom*DF + lane] : 0.f;

  // layer 1: z1[h] = b1[h] + sum_d x[d]*W1[d][h]   (lane = h)
  float z1 = sb1[lane];
  #pragma unroll
  for (int d = 0; d < DF; ++d)
    z1 = fmaf(__shfl(xv, d), sW1[d*H1 + lane], z1);
  float a1 = softplus_f(z1);

  // layer 2: lanes duplicated mod 32 (lane&31 = h2)
  const int h2l = lane & (H2-1);
  float z2 = sb2[h2l];
  #pragma unroll
  for (int h = 0; h < H1; ++h)
    z2 = fmaf(__shfl(a1, h), sW2[h*H2 + h2l], z2);
  float a2 = softplus_f(z2);

  // Ei = b3 + sum_h2 a2*W3 ;  g2 = sigmoid(z2)*W3 ; sigmoid(z)=1-exp(-softplus(z))
  float w3  = sW3[h2l];
  float eip = a2 * w3;
  #pragma unroll
  for (int off = 16; off; off >>= 1) eip += __shfl_xor(eip, off);
  float g2 = (1.f - expf(-a2)) * w3;

  // g1[h] = sigmoid(z1[h]) * sum_h2 g2[h2]*W2[h][h2]
  float t1 = 0.f;
  #pragma unroll
  for (int h2 = 0; h2 < H2; ++h2)
    t1 = fmaf(__shfl(g2, h2), sW2T[h2*H1 + lane], t1);
  float g1 = (1.f - expf(-a1)) * t1;

  // dG[d] = sum_h g1[h]*W1[d][h]    (lane = d, lanes 0..41)
  const int dl = (lane < DF) ? lane : 0;
  float s = 0.f;
  #pragma unroll
  for (int h = 0; h < H1; ++h)
    s = fmaf(__shfl(g1, h), sW1T[h*DF + dl], s);

  if (lane < DF) dG[atom*DF + lane] = s;
  if (lane == 0) Ei_ws[atom] = eip + b3[0];
}

// ---------------- Kernel 2: Force[b,i,c] = sum_{j,f} dG[b,j,f]*dfeat[b,i,j,f,c]
// grid = B*N blocks (one per (b,i)), 256 threads. NO LDS staging: each dG
// element is used exactly once per block, and dG (344 KB total, 43 KB/batch
// shared by 256 blocks) is L2-resident. Dropping the 43 KB LDS tile lifts
// occupancy 3 -> 8 blocks/CU, making all 2048 blocks co-resident (no tail),
// and removes the staging head-phase + barrier. dfeat loads are non-temporal
// so the 264 MB stream doesn't evict dG from L2.
__global__ __launch_bounds__(256, 8) void k2_force(
    const float* __restrict__ dfeat,
    const float* __restrict__ dG,
    const float* __restrict__ Ei_ws,
    float* __restrict__ out) {
  __shared__ float red[4][3];
  __shared__ float ered[4];

  const int tid = threadIdx.x;
  const int bid = blockIdx.x;
  const int b = bid >> 8;           // batch
  const int i = bid & 255;          // atom i

  if (i == 0) {   // fold Etot[b] reduction into one block per batch
    float e = Ei_ws[b*NATOM + tid];
    #pragma unroll
    for (int off = 32; off; off >>= 1) e += __shfl_down(e, off);
    if ((tid & 63) == 0) ered[tid >> 6] = e;
  }

  const f32x4* __restrict__ dgg = (const f32x4*)(dG + b*(NATOM*DF));
  const f32x4* __restrict__ p4 =
      (const f32x4*)(dfeat + (size_t)bid * (NATOM*DF*3));

  float ax = 0.f, ay = 0.f, az = 0.f;
  // 2688 groups of 12 floats; group u: k = 4u..4u+3 (= j*DF+f), c pattern static.
  // Compile-time trip count: 10 uniform iters + peeled half-iter (tid<128).
  #pragma unroll 2
  for (int it = 0; it < 10; ++it) {
    const int u = tid + it * 256;
    f32x4 v0 = __builtin_nontemporal_load(p4 + 3*u + 0);
    f32x4 v1 = __builtin_nontemporal_load(p4 + 3*u + 1);
    f32x4 v2 = __builtin_nontemporal_load(p4 + 3*u + 2);
    f32x4 g  = dgg[u];
    ax += g.x*v0.x + g.y*v0.w + g.z*v1.z + g.w*v2.y;
    ay += g.x*v0.y + g.y*v1.x + g.z*v1.w + g.w*v2.z;
    az += g.x*v0.z + g.y*v1.y + g.z*v2.x + g.w*v2.w;
  }
  if (tid < 128) {
    const int u = tid + 2560;
    f32x4 v0 = __builtin_nontemporal_load(p4 + 3*u + 0);
    f32x4 v1 = __builtin_nontemporal_load(p4 + 3*u + 1);
    f32x4 v2 = __builtin_nontemporal_load(p4 + 3*u + 2);
    f32x4 g  = dgg[u];
    ax += g.x*v0.x + g.y*v0.w + g.z*v1.z + g.w*v2.y;
    ay += g.x*v0.y + g.y*v1.x + g.z*v1.w + g.w*v2.z;
    az += g.x*v0.z + g.y*v1.y + g.z*v2.x + g.w*v2.w;
  }

  #pragma unroll
  for (int off = 32; off; off >>= 1) {
    ax += __shfl_down(ax, off);
    ay += __shfl_down(ay, off);
    az += __shfl_down(az, off);
  }
  const int wv = tid >> 6;
  if ((tid & 63) == 0) { red[wv][0] = ax; red[wv][1] = ay; red[wv][2] = az; }
  __syncthreads();
  if (tid == 0) {
    out[BATCH + (size_t)bid*3 + 0] = red[0][0]+red[1][0]+red[2][0]+red[3][0];
    out[BATCH + (size_t)bid*3 + 1] = red[0][1]+red[1][1]+red[2][1]+red[3][1];
    out[BATCH + (size_t)bid*3 + 2] = red[0][2]+red[1][2]+red[2][2]+red[3][2];
    if (i == 0) out[b] = ered[0] + ered[1] + ered[2] + ered[3];
  }
}

extern "C" void kernel_launch(void* const* d_in, const int* in_sizes, int n_in,
                              void* d_out, int out_size, void* d_ws, size_t ws_size,
                              hipStream_t stream) {
  const float* image = (const float*)d_in[0];
  const float* dfeat = (const float*)d_in[1];
  const float* W1    = (const float*)d_in[2];
  const float* b1    = (const float*)d_in[3];
  const float* W2    = (const float*)d_in[4];
  const float* b2    = (const float*)d_in[5];
  const float* W3    = (const float*)d_in[6];
  const float* b3    = (const float*)d_in[7];
  float* out = (float*)d_out;

  float* dG = (float*)d_ws;                       // B*N*DF floats
  float* Ei = dG + BATCH*NATOM*DF;                // B*N floats

  k1_mlp<<<BATCH*NATOM/4, 256, 0, stream>>>(image, W1, b1, W2, b2, W3, b3, dG, Ei);
  k2_force<<<BATCH*NATOM, 256, 0, stream>>>(dfeat, dG, Ei, out);
}

// Round 4
// 77.705 us; speedup vs baseline: 1.0122x; 1.0122x over previous
//
#include <hip/hip_runtime.h>

#define BATCH 8
#define NATOM 256
#define DF    42
#define H1    64
#define H2    32

typedef float f32x4 __attribute__((ext_vector_type(4)));

__device__ __forceinline__ float softplus_f(float z) {
  return fmaxf(z, 0.f) + log1pf(expf(-fabsf(z)));
}

// ---------------- Kernel 1: per-atom mirrored MLP (fwd + analytic bwd) ----
// grid = B*N/4 blocks, 256 threads (4 waves). One wave per atom.
__global__ __launch_bounds__(256) void k1_mlp(
    const float* __restrict__ image,
    const float* __restrict__ W1, const float* __restrict__ b1,
    const float* __restrict__ W2, const float* __restrict__ b2,
    const float* __restrict__ W3, const float* __restrict__ b3,
    float* __restrict__ dG, float* __restrict__ Ei_ws) {
  __shared__ float sW1 [DF*H1];   // [d][h]
  __shared__ float sW1T[H1*DF];   // [h][d]
  __shared__ float sW2 [H1*H2];   // [h1][h2]
  __shared__ float sW2T[H2*H1];   // [h2][h1]
  __shared__ float sW3[H2], sb1[H1], sb2[H2];

  const int tid = threadIdx.x;
  for (int idx = tid; idx < DF*H1; idx += 256) {
    float w = W1[idx];
    sW1[idx] = w;
    sW1T[(idx & (H1-1))*DF + (idx >> 6)] = w;   // idx = d*64+h
  }
  for (int idx = tid; idx < H1*H2; idx += 256) {
    float w = W2[idx];
    sW2[idx] = w;
    sW2T[(idx & (H2-1))*H1 + (idx >> 5)] = w;   // idx = h1*32+h2
  }
  if (tid < H2)                    { sW3[tid] = W3[tid]; sb2[tid] = b2[tid]; }
  else if (tid >= 64 && tid < 128) { sb1[tid-64] = b1[tid-64]; }
  __syncthreads();

  const int lane = tid & 63;
  const int atom = blockIdx.x * 4 + (tid >> 6);      // 0..B*N-1

  float xv = (lane < DF) ? image[atom*DF + lane] : 0.f;

  // layer 1: z1[h] = b1[h] + sum_d x[d]*W1[d][h]   (lane = h)
  float z1 = sb1[lane];
  #pragma unroll
  for (int d = 0; d < DF; ++d)
    z1 = fmaf(__shfl(xv, d), sW1[d*H1 + lane], z1);
  float a1 = softplus_f(z1);

  // layer 2: lanes duplicated mod 32 (lane&31 = h2)
  const int h2l = lane & (H2-1);
  float z2 = sb2[h2l];
  #pragma unroll
  for (int h = 0; h < H1; ++h)
    z2 = fmaf(__shfl(a1, h), sW2[h*H2 + h2l], z2);
  float a2 = softplus_f(z2);

  // Ei = b3 + sum_h2 a2*W3 ;  g2 = sigmoid(z2)*W3 ; sigmoid(z)=1-exp(-softplus(z))
  float w3  = sW3[h2l];
  float eip = a2 * w3;
  #pragma unroll
  for (int off = 16; off; off >>= 1) eip += __shfl_xor(eip, off);
  float g2 = (1.f - expf(-a2)) * w3;

  // g1[h] = sigmoid(z1[h]) * sum_h2 g2[h2]*W2[h][h2]
  float t1 = 0.f;
  #pragma unroll
  for (int h2 = 0; h2 < H2; ++h2)
    t1 = fmaf(__shfl(g2, h2), sW2T[h2*H1 + lane], t1);
  float g1 = (1.f - expf(-a1)) * t1;

  // dG[d] = sum_h g1[h]*W1[d][h]    (lane = d, lanes 0..41)
  const int dl = (lane < DF) ? lane : 0;
  float s = 0.f;
  #pragma unroll
  for (int h = 0; h < H1; ++h)
    s = fmaf(__shfl(g1, h), sW1T[h*DF + dl], s);

  if (lane < DF) dG[atom*DF + lane] = s;
  if (lane == 0) Ei_ws[atom] = eip + b3[0];
}

// ---------------- Kernel 2: Force[b,i,c] = sum_{j,f} dG[b,j,f]*dfeat[b,i,j,f,c]
// grid = B*N blocks (one per (b,i)), 256 threads, 4 blocks/CU (128 VGPR cap:
// 16 waves/CU, 2048 blocks = exactly 2 dispatch rounds). No LDS staging (dG
// has zero intra-block reuse; 43 KB/batch stays L2-resident). unroll 5 keeps
// ~20 dwordx4 in flight per wave -> ~5 KB/CU, matching the BW*latency product.
__global__ __launch_bounds__(256, 4) void k2_force(
    const float* __restrict__ dfeat,
    const float* __restrict__ dG,
    const float* __restrict__ Ei_ws,
    float* __restrict__ out) {
  __shared__ float red[4][3];
  __shared__ float ered[4];

  const int tid = threadIdx.x;
  const int bid = blockIdx.x;
  const int b = bid >> 8;           // batch
  const int i = bid & 255;          // atom i

  if (i == 0) {   // fold Etot[b] reduction into one block per batch
    float e = Ei_ws[b*NATOM + tid];
    #pragma unroll
    for (int off = 32; off; off >>= 1) e += __shfl_down(e, off);
    if ((tid & 63) == 0) ered[tid >> 6] = e;
  }

  const f32x4* __restrict__ dgg = (const f32x4*)(dG + b*(NATOM*DF));
  const f32x4* __restrict__ p4 =
      (const f32x4*)(dfeat + (size_t)bid * (NATOM*DF*3));

  float ax = 0.f, ay = 0.f, az = 0.f;
  // 2688 groups of 12 floats; group u: k = 4u..4u+3 (= j*DF+f), c pattern static.
  // 10 uniform iters (unroll 5) + peeled half-iter (tid<128).
  #pragma unroll 5
  for (int it = 0; it < 10; ++it) {
    const int u = tid + it * 256;
    f32x4 v0 = __builtin_nontemporal_load(p4 + 3*u + 0);
    f32x4 v1 = __builtin_nontemporal_load(p4 + 3*u + 1);
    f32x4 v2 = __builtin_nontemporal_load(p4 + 3*u + 2);
    f32x4 g  = dgg[u];
    ax += g.x*v0.x + g.y*v0.w + g.z*v1.z + g.w*v2.y;
    ay += g.x*v0.y + g.y*v1.x + g.z*v1.w + g.w*v2.z;
    az += g.x*v0.z + g.y*v1.y + g.z*v2.x + g.w*v2.w;
  }
  if (tid < 128) {
    const int u = tid + 2560;
    f32x4 v0 = __builtin_nontemporal_load(p4 + 3*u + 0);
    f32x4 v1 = __builtin_nontemporal_load(p4 + 3*u + 1);
    f32x4 v2 = __builtin_nontemporal_load(p4 + 3*u + 2);
    f32x4 g  = dgg[u];
    ax += g.x*v0.x + g.y*v0.w + g.z*v1.z + g.w*v2.y;
    ay += g.x*v0.y + g.y*v1.x + g.z*v1.w + g.w*v2.z;
    az += g.x*v0.z + g.y*v1.y + g.z*v2.x + g.w*v2.w;
  }

  #pragma unroll
  for (int off = 32; off; off >>= 1) {
    ax += __shfl_down(ax, off);
    ay += __shfl_down(ay, off);
    az += __shfl_down(az, off);
  }
  const int wv = tid >> 6;
  if ((tid & 63) == 0) { red[wv][0] = ax; red[wv][1] = ay; red[wv][2] = az; }
  __syncthreads();
  if (tid == 0) {
    out[BATCH + (size_t)bid*3 + 0] = red[0][0]+red[1][0]+red[2][0]+red[3][0];
    out[BATCH + (size_t)bid*3 + 1] = red[0][1]+red[1][1]+red[2][1]+red[3][1];
    out[BATCH + (size_t)bid*3 + 2] = red[0][2]+red[1][2]+red[2][2]+red[3][2];
    if (i == 0) out[b] = ered[0] + ered[1] + ered[2] + ered[3];
  }
}

extern "C" void kernel_launch(void* const* d_in, const int* in_sizes, int n_in,
                              void* d_out, int out_size, void* d_ws, size_t ws_size,
                              hipStream_t stream) {
  const float* image = (const float*)d_in[0];
  const float* dfeat = (const float*)d_in[1];
  const float* W1    = (const float*)d_in[2];
  const float* b1    = (const float*)d_in[3];
  const float* W2    = (const float*)d_in[4];
  const float* b2    = (const float*)d_in[5];
  const float* W3    = (const float*)d_in[6];
  const float* b3    = (const float*)d_in[7];
  float* out = (float*)d_out;

  float* dG = (float*)d_ws;                       // B*N*DF floats
  float* Ei = dG + BATCH*NATOM*DF;                // B*N floats

  k1_mlp<<<BATCH*NATOM/4, 256, 0, stream>>>(image, W1, b1, W2, b2, W3, b3, dG, Ei);
  k2_force<<<BATCH*NATOM, 256, 0, stream>>>(dfeat, dG, Ei, out);
}

// Round 5
// 57.375 us; speedup vs baseline: 1.3709x; 1.3543x over previous
//
#include <hip/hip_runtime.h>

#define BATCH 8
#define NATOM 256
#define DF    42
#define H1    64
#define H2    32

typedef float f32x4 __attribute__((ext_vector_type(4)));

__device__ __forceinline__ float softplus_f(float z) {
  return fmaxf(z, 0.f) + log1pf(expf(-fabsf(z)));
}

// ---------------- Kernel 1: per-atom mirrored MLP (fwd + analytic bwd) ----
// grid = B*N/4 blocks, 256 threads (4 waves). One wave per atom.
__global__ __launch_bounds__(256) void k1_mlp(
    const float* __restrict__ image,
    const float* __restrict__ W1, const float* __restrict__ b1,
    const float* __restrict__ W2, const float* __restrict__ b2,
    const float* __restrict__ W3, const float* __restrict__ b3,
    float* __restrict__ dG, float* __restrict__ Ei_ws) {
  __shared__ float sW1 [DF*H1];   // [d][h]
  __shared__ float sW1T[H1*DF];   // [h][d]
  __shared__ float sW2 [H1*H2];   // [h1][h2]
  __shared__ float sW2T[H2*H1];   // [h2][h1]
  __shared__ float sW3[H2], sb1[H1], sb2[H2];

  const int tid = threadIdx.x;
  for (int idx = tid; idx < DF*H1; idx += 256) {
    float w = W1[idx];
    sW1[idx] = w;
    sW1T[(idx & (H1-1))*DF + (idx >> 6)] = w;   // idx = d*64+h
  }
  for (int idx = tid; idx < H1*H2; idx += 256) {
    float w = W2[idx];
    sW2[idx] = w;
    sW2T[(idx & (H2-1))*H1 + (idx >> 5)] = w;   // idx = h1*32+h2
  }
  if (tid < H2)                    { sW3[tid] = W3[tid]; sb2[tid] = b2[tid]; }
  else if (tid >= 64 && tid < 128) { sb1[tid-64] = b1[tid-64]; }
  __syncthreads();

  const int lane = tid & 63;
  const int atom = blockIdx.x * 4 + (tid >> 6);      // 0..B*N-1

  float xv = (lane < DF) ? image[atom*DF + lane] : 0.f;

  // layer 1: z1[h] = b1[h] + sum_d x[d]*W1[d][h]   (lane = h)
  float z1 = sb1[lane];
  #pragma unroll
  for (int d = 0; d < DF; ++d)
    z1 = fmaf(__shfl(xv, d), sW1[d*H1 + lane], z1);
  float a1 = softplus_f(z1);

  // layer 2: lanes duplicated mod 32 (lane&31 = h2)
  const int h2l = lane & (H2-1);
  float z2 = sb2[h2l];
  #pragma unroll
  for (int h = 0; h < H1; ++h)
    z2 = fmaf(__shfl(a1, h), sW2[h*H2 + h2l], z2);
  float a2 = softplus_f(z2);

  // Ei = b3 + sum_h2 a2*W3 ;  g2 = sigmoid(z2)*W3 ; sigmoid(z)=1-exp(-softplus(z))
  float w3  = sW3[h2l];
  float eip = a2 * w3;
  #pragma unroll
  for (int off = 16; off; off >>= 1) eip += __shfl_xor(eip, off);
  float g2 = (1.f - expf(-a2)) * w3;

  // g1[h] = sigmoid(z1[h]) * sum_h2 g2[h2]*W2[h][h2]
  float t1 = 0.f;
  #pragma unroll
  for (int h2 = 0; h2 < H2; ++h2)
    t1 = fmaf(__shfl(g2, h2), sW2T[h2*H1 + lane], t1);
  float g1 = (1.f - expf(-a1)) * t1;

  // dG[d] = sum_h g1[h]*W1[d][h]    (lane = d, lanes 0..41)
  const int dl = (lane < DF) ? lane : 0;
  float s = 0.f;
  #pragma unroll
  for (int h = 0; h < H1; ++h)
    s = fmaf(__shfl(g1, h), sW1T[h*DF + dl], s);

  if (lane < DF) dG[atom*DF + lane] = s;
  if (lane == 0) Ei_ws[atom] = eip + b3[0];
}

// ---------------- Kernel 2: Force[b,i,c] = sum_{j,f} dG[b,j,f]*dfeat[b,i,j,f,c]
// grid = 512 blocks x 512 threads (8 waves). Block blk owns 4 complete rows
// R = blk*4+r, all in batch b = blk>>6 -> dG[b] staged to LDS ONCE per 516 KB
// of dfeat streamed (4x better amortization than one-row blocks). 512 blocks
// at 43 KB LDS = exactly 2 blocks/CU co-resident in ONE round: no tail.
// dG stays in LDS (lgkmcnt) so the dfeat stream owns the vmcnt queue alone.
// No barriers between rows: per-row partials land in distinct LDS slots,
// one barrier + 12-thread finale at the end.
__global__ __launch_bounds__(512, 4) void k2_force(
    const float* __restrict__ dfeat,
    const float* __restrict__ dG,
    const float* __restrict__ Ei_ws,
    float* __restrict__ out) {
  __shared__ f32x4 dgL[NATOM*DF/4];     // 2688 float4 = 43008 B
  __shared__ float red[4][8][3];        // [row][wave][c]
  __shared__ float ered[4];

  const int tid = threadIdx.x;
  const int blk = blockIdx.x;
  const int b = blk >> 6;               // batch (constant per block)

  // stage dG[b] -> LDS: 2688 float4 over 512 threads = 5 full + 128-tail
  const f32x4* __restrict__ dgg = (const f32x4*)(dG + b*(NATOM*DF));
  #pragma unroll
  for (int m = 0; m < 5; ++m) dgL[tid + m*512] = dgg[tid + m*512];
  if (tid < 128) dgL[tid + 2560] = dgg[tid + 2560];

  // fold Etot[b]: first block of each batch reduces Ei (waves 0-3)
  if ((blk & 63) == 0 && tid < 256) {
    float e = Ei_ws[b*NATOM + tid];
    #pragma unroll
    for (int off = 32; off; off >>= 1) e += __shfl_down(e, off);
    if ((tid & 63) == 0) ered[tid >> 6] = e;
  }
  __syncthreads();

  const int wv = tid >> 6;
  // 4 rows, no barriers in between
  for (int r = 0; r < 4; ++r) {
    const int R = blk*4 + r;                       // global row (b,i)
    const f32x4* __restrict__ p4 = (const f32x4*)(dfeat + (size_t)R * (NATOM*DF*3));

    float ax = 0.f, ay = 0.f, az = 0.f;
    // 2688 groups of 12 floats: group g -> dfeat float4 3g..3g+2, dG float4 g.
    #pragma unroll
    for (int m = 0; m < 5; ++m) {
      const int g = tid + m*512;
      f32x4 v0 = p4[3*g + 0];
      f32x4 v1 = p4[3*g + 1];
      f32x4 v2 = p4[3*g + 2];
      f32x4 gg = dgL[g];
      ax += gg.x*v0.x + gg.y*v0.w + gg.z*v1.z + gg.w*v2.y;
      ay += gg.x*v0.y + gg.y*v1.x + gg.z*v1.w + gg.w*v2.z;
      az += gg.x*v0.z + gg.y*v1.y + gg.z*v2.x + gg.w*v2.w;
    }
    if (tid < 128) {
      const int g = tid + 2560;
      f32x4 v0 = p4[3*g + 0];
      f32x4 v1 = p4[3*g + 1];
      f32x4 v2 = p4[3*g + 2];
      f32x4 gg = dgL[g];
      ax += gg.x*v0.x + gg.y*v0.w + gg.z*v1.z + gg.w*v2.y;
      ay += gg.x*v0.y + gg.y*v1.x + gg.z*v1.w + gg.w*v2.z;
      az += gg.x*v0.z + gg.y*v1.y + gg.z*v2.x + gg.w*v2.w;
    }

    #pragma unroll
    for (int off = 32; off; off >>= 1) {
      ax += __shfl_down(ax, off);
      ay += __shfl_down(ay, off);
      az += __shfl_down(az, off);
    }
    if ((tid & 63) == 0) { red[r][wv][0] = ax; red[r][wv][1] = ay; red[r][wv][2] = az; }
  }

  __syncthreads();
  if (tid < 12) {             // 4 rows x 3 components
    const int r = tid >> 2 == 0 ? tid / 3 : tid / 3;  // r = tid/3
    const int c = tid - (tid/3)*3;
    float s = 0.f;
    #pragma unroll
    for (int w = 0; w < 8; ++w) s += red[tid/3][w][c];
    out[BATCH + (size_t)(blk*4 + tid/3)*3 + c] = s;
  }
  if ((blk & 63) == 0 && tid == 12)
    out[b] = ered[0] + ered[1] + ered[2] + ered[3];
}

extern "C" void kernel_launch(void* const* d_in, const int* in_sizes, int n_in,
                              void* d_out, int out_size, void* d_ws, size_t ws_size,
                              hipStream_t stream) {
  const float* image = (const float*)d_in[0];
  const float* dfeat = (const float*)d_in[1];
  const float* W1    = (const float*)d_in[2];
  const float* b1    = (const float*)d_in[3];
  const float* W2    = (const float*)d_in[4];
  const float* b2    = (const float*)d_in[5];
  const float* W3    = (const float*)d_in[6];
  const float* b3    = (const float*)d_in[7];
  float* out = (float*)d_out;

  float* dG = (float*)d_ws;                       // B*N*DF floats
  float* Ei = dG + BATCH*NATOM*DF;                // B*N floats

  k1_mlp<<<BATCH*NATOM/4, 256, 0, stream>>>(image, W1, b1, W2, b2, W3, b3, dG, Ei);
  k2_force<<<BATCH*NATOM/4, 512, 0, stream>>>(dfeat, dG, Ei, out);
}

// Round 6
// 57.307 us; speedup vs baseline: 1.3725x; 1.0012x over previous
//
#include <hip/hip_runtime.h>

#define BATCH 8
#define NATOM 256
#define DF    42
#define H1    64
#define H2    32

typedef float f32x4 __attribute__((ext_vector_type(4)));

__device__ __forceinline__ float softplus_f(float z) {
  return fmaxf(z, 0.f) + log1pf(expf(-fabsf(z)));
}

// ---------------- Kernel 1: per-atom mirrored MLP (fwd + analytic bwd) ----
// grid = B*N/4 blocks, 256 threads (4 waves). One wave per atom.
__global__ __launch_bounds__(256) void k1_mlp(
    const float* __restrict__ image,
    const float* __restrict__ W1, const float* __restrict__ b1,
    const float* __restrict__ W2, const float* __restrict__ b2,
    const float* __restrict__ W3, const float* __restrict__ b3,
    float* __restrict__ dG, float* __restrict__ Ei_ws) {
  __shared__ float sW1 [DF*H1];   // [d][h]
  __shared__ float sW1T[H1*DF];   // [h][d]
  __shared__ float sW2 [H1*H2];   // [h1][h2]
  __shared__ float sW2T[H2*H1];   // [h2][h1]
  __shared__ float sW3[H2], sb1[H1], sb2[H2];

  const int tid = threadIdx.x;
  for (int idx = tid; idx < DF*H1; idx += 256) {
    float w = W1[idx];
    sW1[idx] = w;
    sW1T[(idx & (H1-1))*DF + (idx >> 6)] = w;   // idx = d*64+h
  }
  for (int idx = tid; idx < H1*H2; idx += 256) {
    float w = W2[idx];
    sW2[idx] = w;
    sW2T[(idx & (H2-1))*H1 + (idx >> 5)] = w;   // idx = h1*32+h2
  }
  if (tid < H2)                    { sW3[tid] = W3[tid]; sb2[tid] = b2[tid]; }
  else if (tid >= 64 && tid < 128) { sb1[tid-64] = b1[tid-64]; }
  __syncthreads();

  const int lane = tid & 63;
  const int atom = blockIdx.x * 4 + (tid >> 6);      // 0..B*N-1

  float xv = (lane < DF) ? image[atom*DF + lane] : 0.f;

  // layer 1: z1[h] = b1[h] + sum_d x[d]*W1[d][h]   (lane = h)
  float z1 = sb1[lane];
  #pragma unroll
  for (int d = 0; d < DF; ++d)
    z1 = fmaf(__shfl(xv, d), sW1[d*H1 + lane], z1);
  float a1 = softplus_f(z1);

  // layer 2: lanes duplicated mod 32 (lane&31 = h2)
  const int h2l = lane & (H2-1);
  float z2 = sb2[h2l];
  #pragma unroll
  for (int h = 0; h < H1; ++h)
    z2 = fmaf(__shfl(a1, h), sW2[h*H2 + h2l], z2);
  float a2 = softplus_f(z2);

  // Ei = b3 + sum_h2 a2*W3 ;  g2 = sigmoid(z2)*W3 ; sigmoid(z)=1-exp(-softplus(z))
  float w3  = sW3[h2l];
  float eip = a2 * w3;
  #pragma unroll
  for (int off = 16; off; off >>= 1) eip += __shfl_xor(eip, off);
  float g2 = (1.f - expf(-a2)) * w3;

  // g1[h] = sigmoid(z1[h]) * sum_h2 g2[h2]*W2[h][h2]
  float t1 = 0.f;
  #pragma unroll
  for (int h2 = 0; h2 < H2; ++h2)
    t1 = fmaf(__shfl(g2, h2), sW2T[h2*H1 + lane], t1);
  float g1 = (1.f - expf(-a1)) * t1;

  // dG[d] = sum_h g1[h]*W1[d][h]    (lane = d, lanes 0..41)
  const int dl = (lane < DF) ? lane : 0;
  float s = 0.f;
  #pragma unroll
  for (int h = 0; h < H1; ++h)
    s = fmaf(__shfl(g1, h), sW1T[h*DF + dl], s);

  if (lane < DF) dG[atom*DF + lane] = s;
  if (lane == 0) Ei_ws[atom] = eip + b3[0];
}

// ---------------- Kernel 2: Force[b,i,c] = sum_{j,f} dG[b,j,f]*dfeat[b,i,j,f,c]
// grid = 512 blocks x 512 threads. Block owns 4 rows of one batch; dG[b]
// staged to LDS once per 516 KB streamed; 2 blocks/CU, one clean round.
// UNIT-STRIDE lane mapping: thread t loads float4 q = tid + 512*m ->
// each wave-instruction covers 1024 contiguous bytes (16 cachelines, vs 48
// for the old stride-48 pattern -> 3x fewer L1/TA transactions). The float4's
// (feature,c) split depends on q%3; elements are accumulated into rotated
// local slots s=(2m+j)%3 (compile-time register wiring, groups of 3 iters),
// using only dG[f0], dG[f0+1] from LDS (f0,rq kept incrementally), then one
// per-thread rotation by tid%3 recovers true (x,y,z) before the reduce.
__global__ __launch_bounds__(512, 4) void k2_force(
    const float* __restrict__ dfeat,
    const float* __restrict__ dG,
    const float* __restrict__ Ei_ws,
    float* __restrict__ out) {
  __shared__ float dgLf[NATOM*DF];      // 10752 floats = 43008 B
  __shared__ float red[4][8][3];        // [row][wave][c]
  __shared__ float ered[4];

  const int tid = threadIdx.x;
  const int blk = blockIdx.x;
  const int b = blk >> 6;               // batch (constant per block)

  // stage dG[b] -> LDS (vectorized): 2688 float4 = 512*5 + 128
  const f32x4* __restrict__ dgg = (const f32x4*)(dG + b*(NATOM*DF));
  f32x4* dgv = (f32x4*)dgLf;
  #pragma unroll
  for (int m = 0; m < 5; ++m) dgv[tid + m*512] = dgg[tid + m*512];
  if (tid < 128) dgv[tid + 2560] = dgg[tid + 2560];

  // fold Etot[b]: first block of each batch reduces Ei (waves 0-3)
  if ((blk & 63) == 0 && tid < 256) {
    float e = Ei_ws[b*NATOM + tid];
    #pragma unroll
    for (int off = 32; off; off >>= 1) e += __shfl_down(e, off);
    if ((tid & 63) == 0) ered[tid >> 6] = e;
  }
  __syncthreads();

  const int wv  = tid >> 6;
  const int f0i = (4*tid)/3;            // feature index of element 4*tid
  const int rqi = tid - (tid/3)*3;      // tid % 3

  for (int r = 0; r < 4; ++r) {
    const f32x4* __restrict__ p4 =
        (const f32x4*)(dfeat + (size_t)(blk*4 + r) * (NATOM*DF*3)) + tid;

    float a0 = 0.f, a1 = 0.f, a2 = 0.f;
    int f0 = f0i, rq = rqi;

    // one float4 q = tid + 512*m: elems k=4q+j, f=k/3, c=k%3=(rqi+(2m+j))%3
    auto iter = [&](int m, float& pa, float& pb, float& pc) {
      f32x4 v = p4[m*512];
      float gLo = dgLf[f0];
      float gHi = dgLf[f0+1];
      float gm1 = (rq < 2) ? gLo : gHi;   // j=1: f = f0 + (rq>=2)
      float gm2 = (rq < 1) ? gLo : gHi;   // j=2: f = f0 + (rq>=1)
      pa = fmaf(v.x, gLo, pa);            // j=0 -> slot (2m)%3
      pb = fmaf(v.y, gm1, pb);            // j=1 -> slot (2m+1)%3
      pc = fmaf(v.z, gm2, pc);            // j=2 -> slot (2m+2)%3
      pa = fmaf(v.w, gHi, pa);            // j=3 -> slot (2m)%3
      f0 += 682 + (rq >= 1 ? 1 : 0);      // 4q += 2048
      rq = (rq >= 1) ? rq - 1 : 2;
    };

    #pragma unroll
    for (int mm = 0; mm < 5; ++mm) {      // 15 uniform iters: slots cycle /3
      iter(3*mm + 0, a0, a1, a2);
      iter(3*mm + 1, a2, a0, a1);
      iter(3*mm + 2, a1, a2, a0);
    }
    if (tid < 384) iter(15, a0, a1, a2);  // 8064 = 512*15 + 384 (waves 0-5)

    // slot s holds true c = (rqi + s) % 3 -> rotate back
    float tx = (rqi == 0) ? a0 : (rqi == 1) ? a2 : a1;
    float ty = (rqi == 0) ? a1 : (rqi == 1) ? a0 : a2;
    float tz = (rqi == 0) ? a2 : (rqi == 1) ? a1 : a0;

    #pragma unroll
    for (int off = 32; off; off >>= 1) {
      tx += __shfl_down(tx, off);
      ty += __shfl_down(ty, off);
      tz += __shfl_down(tz, off);
    }
    if ((tid & 63) == 0) { red[r][wv][0] = tx; red[r][wv][1] = ty; red[r][wv][2] = tz; }
  }

  __syncthreads();
  if (tid < 12) {             // 4 rows x 3 components
    const int rr = tid / 3;
    const int c  = tid - rr*3;
    float s = 0.f;
    #pragma unroll
    for (int w = 0; w < 8; ++w) s += red[rr][w][c];
    out[BATCH + (size_t)(blk*4 + rr)*3 + c] = s;
  }
  if ((blk & 63) == 0 && tid == 12)
    out[b] = ered[0] + ered[1] + ered[2] + ered[3];
}

extern "C" void kernel_launch(void* const* d_in, const int* in_sizes, int n_in,
                              void* d_out, int out_size, void* d_ws, size_t ws_size,
                              hipStream_t stream) {
  const float* image = (const float*)d_in[0];
  const float* dfeat = (const float*)d_in[1];
  const float* W1    = (const float*)d_in[2];
  const float* b1    = (const float*)d_in[3];
  const float* W2    = (const float*)d_in[4];
  const float* b2    = (const float*)d_in[5];
  const float* W3    = (const float*)d_in[6];
  const float* b3    = (const float*)d_in[7];
  float* out = (float*)d_out;

  float* dG = (float*)d_ws;                       // B*N*DF floats
  float* Ei = dG + BATCH*NATOM*DF;                // B*N floats

  k1_mlp<<<BATCH*NATOM/4, 256, 0, stream>>>(image, W1, b1, W2, b2, W3, b3, dG, Ei);
  k2_force<<<BATCH*NATOM/4, 512, 0, stream>>>(dfeat, dG, Ei, out);
}

// Round 7
// 56.422 us; speedup vs baseline: 1.3941x; 1.0157x over previous
//
#include <hip/hip_runtime.h>

#define BATCH 8
#define NATOM 256
#define DF    42
#define H1    64
#define H2    32

typedef float f32x4 __attribute__((ext_vector_type(4)));

__device__ __forceinline__ float softplus_f(float z) {
  return fmaxf(z, 0.f) + log1pf(expf(-fabsf(z)));
}

// ---------------- Kernel 1: per-atom mirrored MLP (fwd + analytic bwd) ----
// grid = B*N/4 blocks, 256 threads (4 waves). One wave per atom.
__global__ __launch_bounds__(256) void k1_mlp(
    const float* __restrict__ image,
    const float* __restrict__ W1, const float* __restrict__ b1,
    const float* __restrict__ W2, const float* __restrict__ b2,
    const float* __restrict__ W3, const float* __restrict__ b3,
    float* __restrict__ dG, float* __restrict__ Ei_ws) {
  __shared__ float sW1 [DF*H1];   // [d][h]
  __shared__ float sW1T[H1*DF];   // [h][d]
  __shared__ float sW2 [H1*H2];   // [h1][h2]
  __shared__ float sW2T[H2*H1];   // [h2][h1]
  __shared__ float sW3[H2], sb1[H1], sb2[H2];

  const int tid = threadIdx.x;
  for (int idx = tid; idx < DF*H1; idx += 256) {
    float w = W1[idx];
    sW1[idx] = w;
    sW1T[(idx & (H1-1))*DF + (idx >> 6)] = w;   // idx = d*64+h
  }
  for (int idx = tid; idx < H1*H2; idx += 256) {
    float w = W2[idx];
    sW2[idx] = w;
    sW2T[(idx & (H2-1))*H1 + (idx >> 5)] = w;   // idx = h1*32+h2
  }
  if (tid < H2)                    { sW3[tid] = W3[tid]; sb2[tid] = b2[tid]; }
  else if (tid >= 64 && tid < 128) { sb1[tid-64] = b1[tid-64]; }
  __syncthreads();

  const int lane = tid & 63;
  const int atom = blockIdx.x * 4 + (tid >> 6);      // 0..B*N-1

  float xv = (lane < DF) ? image[atom*DF + lane] : 0.f;

  // layer 1: z1[h] = b1[h] + sum_d x[d]*W1[d][h]   (lane = h)
  float z1 = sb1[lane];
  #pragma unroll
  for (int d = 0; d < DF; ++d)
    z1 = fmaf(__shfl(xv, d), sW1[d*H1 + lane], z1);
  float a1 = softplus_f(z1);

  // layer 2: lanes duplicated mod 32 (lane&31 = h2)
  const int h2l = lane & (H2-1);
  float z2 = sb2[h2l];
  #pragma unroll
  for (int h = 0; h < H1; ++h)
    z2 = fmaf(__shfl(a1, h), sW2[h*H2 + h2l], z2);
  float a2 = softplus_f(z2);

  // Ei = b3 + sum_h2 a2*W3 ;  g2 = sigmoid(z2)*W3 ; sigmoid(z)=1-exp(-softplus(z))
  float w3  = sW3[h2l];
  float eip = a2 * w3;
  #pragma unroll
  for (int off = 16; off; off >>= 1) eip += __shfl_xor(eip, off);
  float g2 = (1.f - expf(-a2)) * w3;

  // g1[h] = sigmoid(z1[h]) * sum_h2 g2[h2]*W2[h][h2]
  float t1 = 0.f;
  #pragma unroll
  for (int h2 = 0; h2 < H2; ++h2)
    t1 = fmaf(__shfl(g2, h2), sW2T[h2*H1 + lane], t1);
  float g1 = (1.f - expf(-a1)) * t1;

  // dG[d] = sum_h g1[h]*W1[d][h]    (lane = d, lanes 0..41)
  const int dl = (lane < DF) ? lane : 0;
  float s = 0.f;
  #pragma unroll
  for (int h = 0; h < H1; ++h)
    s = fmaf(__shfl(g1, h), sW1T[h*DF + dl], s);

  if (lane < DF) dG[atom*DF + lane] = s;
  if (lane == 0) Ei_ws[atom] = eip + b3[0];
}

// ---------------- Kernel 2: Force[b,i,c] = sum_{j,f} dG[b,j,f]*dfeat[b,i,j,f,c]
// grid = 256 blocks x 1024 threads (16 waves), 1 block/CU, one clean round.
// Each block owns 8 CONTIGUOUS rows (R = blk*8+r) = one contiguous 1.03 MB
// region -> the chip presents only 256 sequential streams to the HBM
// controllers (vs 512 before): tests the DRAM row-buffer-thrash theory.
// dG[b] (b = blk>>5, constant per block) staged to LDS once per 1 MB streamed.
// Unit-stride lane mapping: thread t loads float4 q = tid + 1024*m; the
// (feature,c) split of each float4 is handled with rotated accumulator slots
// s=(m+j)%3 (compile-time wiring in m%3 groups), dG factors from LDS at f0,
// f0+1 (f0,rq maintained incrementally), and a final per-thread rotation by
// tid%3 recovers true (x,y,z) before the shuffle reduce.
__global__ __launch_bounds__(1024, 4) void k2_force(
    const float* __restrict__ dfeat,
    const float* __restrict__ dG,
    const float* __restrict__ Ei_ws,
    float* __restrict__ out) {
  __shared__ float dgLf[NATOM*DF];      // 10752 floats = 43008 B
  __shared__ float red[8][16][3];       // [row][wave][c]
  __shared__ float ered[4];

  const int tid = threadIdx.x;
  const int blk = blockIdx.x;
  const int b = blk >> 5;               // batch (constant per block)

  // stage dG[b] -> LDS (vectorized): 2688 float4 = 1024*2 + 640
  const f32x4* __restrict__ dgg = (const f32x4*)(dG + b*(NATOM*DF));
  f32x4* dgv = (f32x4*)dgLf;
  dgv[tid]        = dgg[tid];
  dgv[tid + 1024] = dgg[tid + 1024];
  if (tid < 640) dgv[tid + 2048] = dgg[tid + 2048];

  // fold Etot[b]: first block of each batch reduces Ei (waves 0-3)
  if ((blk & 31) == 0 && tid < 256) {
    float e = Ei_ws[b*NATOM + tid];
    #pragma unroll
    for (int off = 32; off; off >>= 1) e += __shfl_down(e, off);
    if ((tid & 63) == 0) ered[tid >> 6] = e;
  }
  __syncthreads();

  const int wv  = tid >> 6;
  const int f0i = (4*tid)/3;            // feature index of element 4*tid
  const int rqi = tid - (tid/3)*3;      // tid % 3  (= 4*tid mod 3)

  #pragma unroll 1
  for (int r = 0; r < 8; ++r) {
    const f32x4* __restrict__ p4 =
        (const f32x4*)(dfeat + (size_t)(blk*8 + r) * (NATOM*DF*3)) + tid;

    float a0 = 0.f, a1 = 0.f, a2 = 0.f;
    int f0 = f0i, rq = rqi;             // rq = (rqi + m) % 3 at step m

    // float4 q = tid + 1024*m: elems k=4q+j, c=(rqi+m+j)%3 -> slot (m+j)%3.
    // j=0: f=f0; j=3: f=f0+1; j=1: f=f0+(rq==2); j=2: f=f0+(rq>=1).
    auto iter = [&](float& pa, float& pb, float& pc, int m) {
      f32x4 v = p4[m*1024];
      float gLo = dgLf[f0];
      float gHi = dgLf[f0+1];
      float gm1 = (rq < 2) ? gLo : gHi;
      float gm2 = (rq < 1) ? gLo : gHi;
      pa = fmaf(v.x, gLo, pa);          // j=0 -> slot (m)%3
      pb = fmaf(v.y, gm1, pb);          // j=1 -> slot (m+1)%3
      pc = fmaf(v.z, gm2, pc);          // j=2 -> slot (m+2)%3
      pa = fmaf(v.w, gHi, pa);          // j=3 -> slot (m)%3
      f0 += 1365 + (rq == 2 ? 1 : 0);   // 4q += 4096 = 3*1365 + 1
      rq = (rq == 2) ? 0 : rq + 1;
    };

    // 8064 float4/row = 1024*7 + 896: m=0..6 uniform, m=7 for tid<896
    iter(a0, a1, a2, 0);
    iter(a1, a2, a0, 1);
    iter(a2, a0, a1, 2);
    iter(a0, a1, a2, 3);
    iter(a1, a2, a0, 4);
    iter(a2, a0, a1, 5);
    iter(a0, a1, a2, 6);
    if (tid < 896) iter(a1, a2, a0, 7);

    // slot s holds true c = (rqi + s) % 3 -> rotate back
    float tx = (rqi == 0) ? a0 : (rqi == 1) ? a2 : a1;
    float ty = (rqi == 0) ? a1 : (rqi == 1) ? a0 : a2;
    float tz = (rqi == 0) ? a2 : (rqi == 1) ? a1 : a0;

    #pragma unroll
    for (int off = 32; off; off >>= 1) {
      tx += __shfl_down(tx, off);
      ty += __shfl_down(ty, off);
      tz += __shfl_down(tz, off);
    }
    if ((tid & 63) == 0) { red[r][wv][0] = tx; red[r][wv][1] = ty; red[r][wv][2] = tz; }
  }

  __syncthreads();
  if (tid < 24) {             // 8 rows x 3 components
    const int rr = tid / 3;
    const int c  = tid - rr*3;
    float s = 0.f;
    #pragma unroll
    for (int w = 0; w < 16; ++w) s += red[rr][w][c];
    out[BATCH + (size_t)(blk*8 + rr)*3 + c] = s;
  }
  if ((blk & 31) == 0 && tid == 24)
    out[b] = ered[0] + ered[1] + ered[2] + ered[3];
}

extern "C" void kernel_launch(void* const* d_in, const int* in_sizes, int n_in,
                              void* d_out, int out_size, void* d_ws, size_t ws_size,
                              hipStream_t stream) {
  const float* image = (const float*)d_in[0];
  const float* dfeat = (const float*)d_in[1];
  const float* W1    = (const float*)d_in[2];
  const float* b1    = (const float*)d_in[3];
  const float* W2    = (const float*)d_in[4];
  const float* b2    = (const float*)d_in[5];
  const float* W3    = (const float*)d_in[6];
  const float* b3    = (const float*)d_in[7];
  float* out = (float*)d_out;

  float* dG = (float*)d_ws;                       // B*N*DF floats
  float* Ei = dG + BATCH*NATOM*DF;                // B*N floats

  k1_mlp<<<BATCH*NATOM/4, 256, 0, stream>>>(image, W1, b1, W2, b2, W3, b3, dG, Ei);
  k2_force<<<BATCH*NATOM/8, 1024, 0, stream>>>(dfeat, dG, Ei, out);
}